// Round 1
// baseline (7777.697 us; speedup 1.0000x reference)
//
#include <hip/hip_runtime.h>
#include <math.h>

// Problem constants: x[64][512][512] fp32, W[1024][2048] fp32, b[2048] fp32
// out[64][512][512] fp32.  z = [h,x] @ W + b ; f,i,o,cb = split(z,4)
// c' = sig(f)*c + sig(i)*cb ; h' = sig(o)*c'   (no tanh)
#define Bz 64
#define Tz 512
#define Dz 512
#define Hz 512

// ws layout:
//   Wb   : float [64][1024][32]   (8 MB)   W re-tiled per col-group
//   hbuf : float [2][64][512]     (256 KB) double-buffered h state
//   cbuf : float [4][64][128]     (128 KB) c state per (sg,cg,tid)
#define WB_FLOATS   (64*1024*32)
#define HBUF_FLOATS (64*512)

__global__ __launch_bounds__(256) void zero_ws(float* __restrict__ p, int n) {
    int i = blockIdx.x * 256 + threadIdx.x;
    if (i < n) p[i] = 0.0f;
}

// Wb[cg][k][c] = W[k][g*512 + cg*8 + hc], c = g*8+hc
__global__ __launch_bounds__(256) void prep_w(const float* __restrict__ W,
                                              float* __restrict__ Wb) {
    int k = blockIdx.x;  // 0..1023
    for (int it = 0; it < 8; ++it) {
        int col = it * 256 + threadIdx.x;          // 0..2047
        float v = W[(size_t)k * 2048 + col];
        int g = col >> 9, rem = col & 511;
        int cg = rem >> 3, hc = rem & 7;
        int c = g * 8 + hc;
        Wb[((size_t)cg * 1024 + k) * 32 + c] = v;
    }
}

// One timestep. grid = (64 col-groups, 4 seq-groups), block = 256.
// Block computes z[16 s][32 c] = A[16 s][1024 k] * Wb[cg][1024 k][32 c]
// with A = [h | x_t], then gates + state update for its 16x8 (s,hc) cells.
__global__ __launch_bounds__(256) void lstm_step(
    const float* __restrict__ x,      // [64][512][512]
    const float* __restrict__ bias,   // [2048]
    const float* __restrict__ Wb,     // [64][1024][32]
    const float* __restrict__ hbr,    // h in : [64][512]
    float* __restrict__ hbw,          // h out: [64][512]
    float* __restrict__ cbuf,         // [4][64][128]
    float* __restrict__ out,          // [64][512][512]
    int t)
{
    const int cg  = blockIdx.x;   // 0..63
    const int sg  = blockIdx.y;   // 0..3
    const int tid = threadIdx.x;

    __shared__ float As[16 * 1028];     // A[s][k], padded stride (bank shift 4)
    __shared__ float zpart[8 * 512];    // [kw][s*32+c] partial sums
    __shared__ float zred[512];         // reduced z [s*32+c]

    // ---- stage A: k<512 -> h, k>=512 -> x[b][t][k-512] ---------------------
    for (int it = 0; it < 16; ++it) {
        int fi = it * 256 + tid;        // float4 index, 0..4095
        int s  = fi >> 8;               // 16 rows x 256 float4
        int k  = (fi & 255) * 4;
        const float* src;
        if (k < 512) src = hbr + (sg * 16 + s) * 512 + k;
        else         src = x + (size_t)(sg * 16 + s) * Tz * Dz
                             + (size_t)t * Dz + (k - 512);
        float4 v = *(const float4*)src;
        *(float4*)(As + s * 1028 + k) = v;
    }
    __syncthreads();

    // ---- GEMM: thread = (ct 0..7, st 0..3, kw 0..7); tile 4s x 4c, K/8 ----
    const int ct = tid & 7;
    const int st = (tid >> 3) & 3;
    const int kw = tid >> 5;

    float acc[4][4];
#pragma unroll
    for (int i = 0; i < 4; ++i)
#pragma unroll
        for (int j = 0; j < 4; ++j) acc[i][j] = 0.0f;

    const float* wp = Wb + (size_t)cg * 1024 * 32 + (size_t)(kw * 128) * 32 + ct * 4;
    const float* ap = As + st * 4 * 1028 + kw * 128;

#pragma unroll 4
    for (int kk = 0; kk < 128; kk += 4) {
        float4 w0 = *(const float4*)(wp + (kk + 0) * 32);
        float4 w1 = *(const float4*)(wp + (kk + 1) * 32);
        float4 w2 = *(const float4*)(wp + (kk + 2) * 32);
        float4 w3 = *(const float4*)(wp + (kk + 3) * 32);
        float4 a0 = *(const float4*)(ap + 0 * 1028 + kk);
        float4 a1 = *(const float4*)(ap + 1 * 1028 + kk);
        float4 a2 = *(const float4*)(ap + 2 * 1028 + kk);
        float4 a3 = *(const float4*)(ap + 3 * 1028 + kk);
#define FMA_ROW(i, ai)                                              \
        acc[i][0] += ai.x * w0.x + ai.y * w1.x + ai.z * w2.x + ai.w * w3.x; \
        acc[i][1] += ai.x * w0.y + ai.y * w1.y + ai.z * w2.y + ai.w * w3.y; \
        acc[i][2] += ai.x * w0.z + ai.y * w1.z + ai.z * w2.z + ai.w * w3.z; \
        acc[i][3] += ai.x * w0.w + ai.y * w1.w + ai.z * w2.w + ai.w * w3.w;
        FMA_ROW(0, a0)
        FMA_ROW(1, a1)
        FMA_ROW(2, a2)
        FMA_ROW(3, a3)
#undef FMA_ROW
    }

    // ---- write K-partials, reduce 8-way ------------------------------------
#pragma unroll
    for (int i = 0; i < 4; ++i) {
        float4 v = make_float4(acc[i][0], acc[i][1], acc[i][2], acc[i][3]);
        *(float4*)(zpart + kw * 512 + (st * 4 + i) * 32 + ct * 4) = v;
    }
    __syncthreads();

    {
        int o = tid * 2;   // two outputs per thread
        float z0 = 0.0f, z1 = 0.0f;
#pragma unroll
        for (int w = 0; w < 8; ++w) {
            float2 v = *(const float2*)(zpart + w * 512 + o);
            z0 += v.x; z1 += v.y;
        }
        *(float2*)(zred + o) = make_float2(z0, z1);
    }
    __syncthreads();

    // ---- epilogue: tid<128 owns (s,hc) -------------------------------------
    if (tid < 128) {
        int s  = tid >> 3;
        int hc = tid & 7;
        int colb = cg * 8 + hc;
        float zf = zred[s * 32 + hc]       + bias[colb];
        float zi = zred[s * 32 + 8 + hc]   + bias[512 + colb];
        float zo = zred[s * 32 + 16 + hc]  + bias[1024 + colb];
        float zc = zred[s * 32 + 24 + hc]  + bias[1536 + colb];

        int cidx = (sg * 64 + cg) * 128 + tid;
        float cold = cbuf[cidx];
        float sf = 1.0f / (1.0f + expf(-zf));
        float si = 1.0f / (1.0f + expf(-zi));
        float so = 1.0f / (1.0f + expf(-zo));
        float cnew = sf * cold + si * zc;
        float h = so * cnew;
        cbuf[cidx] = cnew;

        hbw[(sg * 16 + s) * 512 + colb] = h;
        out[(size_t)(sg * 16 + s) * Tz * Hz + (size_t)t * Hz + colb] = h;
    }
}

extern "C" void kernel_launch(void* const* d_in, const int* in_sizes, int n_in,
                              void* d_out, int out_size, void* d_ws, size_t ws_size,
                              hipStream_t stream) {
    const float* x    = (const float*)d_in[0];
    const float* W    = (const float*)d_in[1];
    const float* bias = (const float*)d_in[2];
    float* out = (float*)d_out;

    char* ws = (char*)d_ws;
    float* Wb   = (float*)ws;
    float* hbuf = (float*)(ws + (size_t)WB_FLOATS * 4);
    float* cbuf = hbuf + 2 * HBUF_FLOATS;

    // zero h (both buffers) + c state: 2*32768 + 32768 = 98304 floats
    zero_ws<<<384, 256, 0, stream>>>(hbuf, 98304);
    prep_w<<<1024, 256, 0, stream>>>(W, Wb);

    for (int t = 0; t < Tz; ++t) {
        float* hr = hbuf + (t & 1) * HBUF_FLOATS;
        float* hw = hbuf + ((t + 1) & 1) * HBUF_FLOATS;
        lstm_step<<<dim3(64, 4), 256, 0, stream>>>(x, bias, Wb, hr, hw, cbuf, out, t);
    }
}